// Round 17
// baseline (25.127 us; speedup 1.0000x reference)
//
#include <hip/hip_runtime.h>

// RuleNet: out[b] = 5 + sum_c rw[c] * min_j( mu[c,j]*x[b,j] + (1-mu[c,j]) )
// x = [x0, 1-x0], mu = sigmoid(conjunctions).
// fit(b,c) = 1 - max_v max( mu1*(1-x), mu2*x );  mu1*(1-x) = fma(-mu1,x,mu1).
//
// R17 = R16 structure + PACKED f32 math (v_pk_fma_f32 / v_pk_mul_f32 /
// v_pk_max_f32 via float2 ext-vectors): 4 pk-instrs per 2v per c vs 6
// scalar -> core VALU count -33% (1536 -> 1024 instrs/wave).
// mu pack order: muT4[vp][c] = (mu1_v, mu1_v+1, mu2_v, mu2_v+1).

#define B_    1024
#define C_    512
#define V_    256
#define TWOV  512

#define BPB    8               // batches per block
#define NBG    (B_ / BPB)      // 128 b-groups
#define NCH    4               // c-chunks of 128 (2 per lane: c, c+64)

typedef float f32x4 __attribute__((ext_vector_type(4)));
typedef float f32x2 __attribute__((ext_vector_type(2)));

#define EFMA(a, b, c) __builtin_elementwise_fma(a, b, c)
#define EMAX(a, b)    __builtin_elementwise_max(a, b)

__device__ __forceinline__ float sigf(float z) {
    return 1.0f / (1.0f + __expf(-z));
}

// ---------- kernel 1: sigmoid + transpose (coalesced writes), + out init ----
// f32x4 muT4[vp][c] = (mu1[2vp], mu1[2vp+1], mu2[2vp], mu2[2vp+1])
__global__ __launch_bounds__(512) void k_prep(const float* __restrict__ conj,
                                              float4* __restrict__ muT4,
                                              float* __restrict__ out) {
    const int vp = blockIdx.x;       // 128 blocks = v-pairs
    const int c  = threadIdx.x;      // 512 threads = conjunctions
    if (vp < 2) out[vp * 512 + c] = 5.0f;
    const int v = vp * 2;
    const float* row = conj + (size_t)c * TWOV;
    float z1a = row[v];
    float z1b = row[v + 1];
    float z2a = row[V_ + v];
    float z2b = row[V_ + v + 1];
    float4 r;
    r.x = sigf(z1a);   // mu1[v]
    r.y = sigf(z1b);   // mu1[v+1]
    r.z = sigf(z2a);   // mu2[v]
    r.w = sigf(z2b);   // mu2[v+1]
    muT4[(size_t)vp * C_ + c] = r;   // coalesced 512 x 16B
}

// ---------- kernel 2: main fuzzy-AND (packed f32 math) ----------
__global__ __launch_bounds__(512, 4) void k_main(const float* __restrict__ x0,
                                                 const f32x4* __restrict__ muT4,
                                                 const float* __restrict__ rw,
                                                 float* __restrict__ out) {
    const int tid  = threadIdx.x;
    const int lane = tid & 63;
    const int wave = tid >> 6;                   // v-eighth owner (32 v)
    const int bg   = blockIdx.x;                 // 128 groups of 8 batches
    const int chunk= blockIdx.y;                 // 4 chunks of 128 c
    const int cA   = chunk * 128 + lane;         // lane's first conjunction
    const int vq   = wave * 8;                   // f32x4 base in xs

    __shared__ f32x4 xs4[BPB * V_ / 4];          // 8 KB x tile
    __shared__ float red[8 * 64 * 17];           // 34 KB epilogue (stride 17)

    // stage x; compiler's vmcnt(0) for the ds_write fires BEFORE asm loads
    {
        const f32x4* xg = reinterpret_cast<const f32x4*>(x0 + (size_t)bg * BPB * V_);
        xs4[tid] = xg[tid];
    }

    const f32x4* pA  = muT4 + (size_t)(wave * 16) * C_ + cA;
    const f32x4* pA1 = pA + C_;

    f32x2 mA2[BPB], mB2[BPB];
#pragma unroll
    for (int i = 0; i < BPB; ++i) { mA2[i] = (f32x2)0.0f; mB2[i] = (f32x2)0.0f; }

    f32x4 A0a, A1a, B0a, B1a, A0b, A1b, B0b, B1b, A0c, A1c, B0c, B1c;

#define ISSUE(A0, A1, Bq0, Bq1) do { \
    asm volatile("global_load_dwordx4 %0, %1, off"             : "=v"(A0)  : "v"(pA));  \
    asm volatile("global_load_dwordx4 %0, %1, off offset:1024" : "=v"(Bq0) : "v"(pA));  \
    asm volatile("global_load_dwordx4 %0, %1, off"             : "=v"(A1)  : "v"(pA1)); \
    asm volatile("global_load_dwordx4 %0, %1, off offset:1024" : "=v"(Bq1) : "v"(pA1)); \
    pA += 2 * C_; pA1 += 2 * C_; } while (0)

    // prologue: q0, q1 in flight (8 outstanding)
    ISSUE(A0a, A1a, B0a, B1a);
    ISSUE(A0b, A1b, B0b, B1b);

    __syncthreads();                             // x tile ready

    // packed fuzzy-AND for batch bi: 16 pk instrs per PAIR (2 c x 4 v)
#define PAIR(XC, bi, A0, A1, Bq0, Bq1) do { \
    f32x2 xlo = XC.xy, xhi = XC.zw; \
    f32x2 ma = mA2[bi], mb = mB2[bi]; \
    ma = EMAX(ma, EMAX(EFMA(-A0.xy,  xlo, A0.xy),  A0.zw  * xlo)); \
    ma = EMAX(ma, EMAX(EFMA(-A1.xy,  xhi, A1.xy),  A1.zw  * xhi)); \
    mb = EMAX(mb, EMAX(EFMA(-Bq0.xy, xlo, Bq0.xy), Bq0.zw * xlo)); \
    mb = EMAX(mb, EMAX(EFMA(-Bq1.xy, xhi, Bq1.xy), Bq1.zw * xhi)); \
    mA2[bi] = ma; mB2[bi] = mb; } while (0)

#define QSTEP(q, CA0, CA1, CB0, CB1, NA0, NA1, NB0, NB1, VMC) do { \
    f32x4 xc0 = xs4[0 * 64 + vq + (q)]; \
    f32x4 xc1 = xs4[1 * 64 + vq + (q)]; \
    f32x4 xc2 = xs4[2 * 64 + vq + (q)]; \
    f32x4 xc3 = xs4[3 * 64 + vq + (q)]; \
    f32x4 xc4 = xs4[4 * 64 + vq + (q)]; \
    f32x4 xc5 = xs4[5 * 64 + vq + (q)]; \
    f32x4 xc6 = xs4[6 * 64 + vq + (q)]; \
    f32x4 xc7 = xs4[7 * 64 + vq + (q)]; \
    if ((q) < 6) ISSUE(NA0, NA1, NB0, NB1); \
    asm volatile("s_waitcnt vmcnt(" #VMC ")" \
                 : "+v"(CA0), "+v"(CA1), "+v"(CB0), "+v"(CB1)); \
    PAIR(xc0, 0, CA0, CA1, CB0, CB1); \
    PAIR(xc1, 1, CA0, CA1, CB0, CB1); \
    PAIR(xc2, 2, CA0, CA1, CB0, CB1); \
    PAIR(xc3, 3, CA0, CA1, CB0, CB1); \
    PAIR(xc4, 4, CA0, CA1, CB0, CB1); \
    PAIR(xc5, 5, CA0, CA1, CB0, CB1); \
    PAIR(xc6, 6, CA0, CA1, CB0, CB1); \
    PAIR(xc7, 7, CA0, CA1, CB0, CB1); } while (0)

    QSTEP(0, A0a, A1a, B0a, B1a,  A0c, A1c, B0c, B1c, 8);
    QSTEP(1, A0b, A1b, B0b, B1b,  A0a, A1a, B0a, B1a, 8);
    QSTEP(2, A0c, A1c, B0c, B1c,  A0b, A1b, B0b, B1b, 8);
    QSTEP(3, A0a, A1a, B0a, B1a,  A0c, A1c, B0c, B1c, 8);
    QSTEP(4, A0b, A1b, B0b, B1b,  A0a, A1a, B0a, B1a, 8);
    QSTEP(5, A0c, A1c, B0c, B1c,  A0b, A1b, B0b, B1b, 8);
    QSTEP(6, A0a, A1a, B0a, B1a,  A0a, A1a, B0a, B1a, 4);   // no issue
    QSTEP(7, A0b, A1b, B0b, B1b,  A0b, A1b, B0b, B1b, 0);   // no issue

#undef QSTEP
#undef PAIR
#undef ISSUE

    // fold packed accumulators to scalars
    float mA[BPB], mB[BPB];
#pragma unroll
    for (int bi = 0; bi < BPB; ++bi) {
        mA[bi] = fmaxf(mA2[bi].x, mA2[bi].y);
        mB[bi] = fmaxf(mB2[bi].x, mB2[bi].y);
    }

    // ---- epilogue: combine 8 v-eighths, weight, sum over c, accumulate ----
#pragma unroll
    for (int bi = 0; bi < BPB; ++bi) {
        red[(wave * 64 + lane) * 17 + bi * 2 + 0] = mA[bi];
        red[(wave * 64 + lane) * 17 + bi * 2 + 1] = mB[bi];
    }
    __syncthreads();

    if (wave < 2) {                              // wave w finishes cc = w
        const float rwc = rw[chunk * 128 + wave * 64 + lane];
        float con0, con1, con2, con3, con4, con5, con6, con7;
#define FIN(bi, CON) do { \
        float mm = red[(0 * 64 + lane) * 17 + (bi) * 2 + wave]; \
        _Pragma("unroll") \
        for (int wv = 1; wv < 8; ++wv) \
            mm = fmaxf(mm, red[(wv * 64 + lane) * 17 + (bi) * 2 + wave]); \
        float v = rwc * (1.0f - mm); \
        v += __shfl_xor(v, 1, 64);  v += __shfl_xor(v, 2, 64); \
        v += __shfl_xor(v, 4, 64);  v += __shfl_xor(v, 8, 64); \
        v += __shfl_xor(v, 16, 64); v += __shfl_xor(v, 32, 64); \
        CON = v; } while (0)
        FIN(0, con0); FIN(1, con1); FIN(2, con2); FIN(3, con3);
        FIN(4, con4); FIN(5, con5); FIN(6, con6); FIN(7, con7);
#undef FIN
        float t0 = (lane & 1) ? con1 : con0;
        float t1 = (lane & 1) ? con3 : con2;
        float t2 = (lane & 1) ? con5 : con4;
        float t3 = (lane & 1) ? con7 : con6;
        float u0 = (lane & 2) ? t1 : t0;
        float u1 = (lane & 2) ? t3 : t2;
        float sel = (lane & 4) ? u1 : u0;
        if (lane < 8)
            atomicAdd(&out[bg * BPB + lane], sel);   // 8 adds/element total
    }
}

// ---------- fallback (ws too small): naive but correct ----------
__global__ __launch_bounds__(256) void k_naive(const float* __restrict__ x0,
                                               const float* __restrict__ conj,
                                               const float* __restrict__ rw,
                                               float* __restrict__ out) {
    int b = blockIdx.x;
    int t = threadIdx.x;
    __shared__ float red[256];
    float acc = 0.0f;
    for (int c = t; c < C_; c += 256) {
        float mm = 0.0f;
        for (int v = 0; v < V_; ++v) {
            float mu1 = 1.0f / (1.0f + expf(-conj[(size_t)c * TWOV + v]));
            float mu2 = 1.0f / (1.0f + expf(-conj[(size_t)c * TWOV + V_ + v]));
            float x = x0[(size_t)b * V_ + v];
            mm = fmaxf(mm, fmaxf(mu1 * (1.0f - x), mu2 * x));
        }
        acc += rw[c] * (1.0f - mm);
    }
    red[t] = acc;
    __syncthreads();
    for (int s = 128; s > 0; s >>= 1) {
        if (t < s) red[t] += red[t + s];
        __syncthreads();
    }
    if (t == 0) out[b] = 5.0f + red[0];
}

extern "C" void kernel_launch(void* const* d_in, const int* in_sizes, int n_in,
                              void* d_out, int out_size, void* d_ws, size_t ws_size,
                              hipStream_t stream) {
    const float* x0   = (const float*)d_in[0];
    const float* conj = (const float*)d_in[1];
    const float* rw   = (const float*)d_in[2];
    float* out = (float*)d_out;

    const size_t mu_floats = (size_t)(V_ / 2) * C_ * 4;   // 262144 floats (1 MB)
    const size_t need = mu_floats * sizeof(float);

    if (ws_size < need) {
        k_naive<<<B_, 256, 0, stream>>>(x0, conj, rw, out);
        return;
    }

    f32x4* muT4 = (f32x4*)d_ws;

    k_prep<<<V_ / 2, 512, 0, stream>>>(conj, (float4*)muT4, out);
    dim3 grid(NBG, NCH);      // 128 x 4 = 512 blocks = 2/CU, 16 waves/CU
    k_main<<<grid, 512, 0, stream>>>(x0, muT4, rw, out);
}

// Round 21
// 20.964 us; speedup vs baseline: 1.1986x; 1.1986x over previous
//
#include <hip/hip_runtime.h>

// RuleNet: out[b] = 5 + sum_c rw[c] * min_j( mu[c,j]*x[b,j] + (1-mu[c,j]) )
// x = [x0, 1-x0], mu = sigmoid(conjunctions).
// fit(b,c) = 1 - max_v max( mu1*(1-x0), mu2*x0 ).
//
// R21 = R20 geometry with the f16 core lowered BY HAND to VOP3P asm
// (v_pk_mul_f16 / v_pk_max_f16 on 32-bit float carriers). R19/R20 lesson:
// identical absmax from two load mechanisms -> suspect = _Float16
// elementwise builtins' lowering. Register-only asm ops are regalloc-safe
// (no async completion), unlike R19's asm loads. x tile stores (x, 1-x)
// f16 pairs so NO fma is needed: both terms are pure pk_mul.

#define B_    1024
#define C_    512
#define V_    256
#define TWOV  512

#define BPB    8               // batches per block
#define NBG    (B_ / BPB)      // 128 b-groups
#define NCH    4               // 4 chunks of 128 c (2 per lane: c, c+64)

typedef float    f32x4 __attribute__((ext_vector_type(4)));
typedef _Float16 h16x2 __attribute__((ext_vector_type(2)));

__device__ __forceinline__ float sigf(float z) {
    return 1.0f / (1.0f + __expf(-z));
}
__device__ __forceinline__ float packh2(float a, float b) {
    h16x2 h; h.x = (_Float16)a; h.y = (_Float16)b;
    return __builtin_bit_cast(float, h);
}

// packed f16 ops, hand-lowered (32-bit float carriers)
#define PKMUL(D, A, Bq) asm("v_pk_mul_f16 %0, %1, %2" : "=v"(D) : "v"(A), "v"(Bq))
#define PKMAX(ACC, T)   asm("v_pk_max_f16 %0, %0, %1" : "+v"(ACC) : "v"(T))

// ---------- kernel 1: sigmoid -> f16 pack, + out=5.0 init ----------
// muH[vq][c] : 16B = { m1(v0,v1), m1(v2,v3), m2(v0,v1), m2(v2,v3) } as f16 pairs
__global__ __launch_bounds__(512) void k_prep(const float* __restrict__ conj,
                                              float4* __restrict__ muH,
                                              float* __restrict__ out) {
    const int vq = blockIdx.x;       // 64 blocks = v-quads
    const int c  = threadIdx.x;      // 512 threads = conjunctions
    if (vq < 2) out[vq * 512 + c] = 5.0f;
    const float* row = conj + (size_t)c * TWOV;
    const int v = vq * 4;
    float4 r;
    r.x = packh2(sigf(row[v + 0]),      sigf(row[v + 1]));
    r.y = packh2(sigf(row[v + 2]),      sigf(row[v + 3]));
    r.z = packh2(sigf(row[V_ + v + 0]), sigf(row[V_ + v + 1]));
    r.w = packh2(sigf(row[V_ + v + 2]), sigf(row[V_ + v + 3]));
    muH[(size_t)vq * C_ + c] = r;    // coalesced 512 x 16B
}

// ---------- kernel 2: main fuzzy-AND (hand-lowered packed f16) ----------
__global__ __launch_bounds__(512, 4) void k_main(const float* __restrict__ x0,
                                                 const float4* __restrict__ muH,
                                                 const float* __restrict__ rw,
                                                 float* __restrict__ out) {
    const int tid  = threadIdx.x;
    const int lane = tid & 63;
    const int wave = tid >> 6;                   // v-eighth owner (32 v = 8 vq)
    const int bg   = blockIdx.x;                 // 128 groups of 8 batches
    const int chunk= blockIdx.y;                 // 4 chunks of 128 c
    const int cA   = chunk * 128 + lane;         // lane's first c (cB = cA+64)
    const int vq0  = wave * 8;                   // this wave's vq base

    __shared__ float4 xs4[BPB * 64];             // 8 KB: [b][vq] {x01,x23,c01,c23}
    __shared__ float  red[8 * 64 * 17];          // 34 KB epilogue (stride 17)

    // stage x as f16 (x, 1-x) pairs; thread -> (b = tid>>6, vq = tid&63)
    {
        const int b = tid >> 6, vq = tid & 63;
        float4 xv = *reinterpret_cast<const float4*>(
            x0 + (size_t)(bg * BPB + b) * V_ + vq * 4);
        float4 pk;
        pk.x = packh2(xv.x, xv.y);               // x      (v0,v1)
        pk.y = packh2(xv.z, xv.w);               // x      (v2,v3)
        pk.z = packh2(1.0f - xv.x, 1.0f - xv.y); // (1-x)  (v0,v1)
        pk.w = packh2(1.0f - xv.z, 1.0f - xv.w); // (1-x)  (v2,v3)
        xs4[tid] = pk;
    }

    const float4* p = muH + (size_t)vq0 * C_ + cA;   // row q at p[q*C_]; cB at +64

    float accA[BPB], accB[BPB];                  // f16x2 carriers
#pragma unroll
    for (int i = 0; i < BPB; ++i) { accA[i] = 0.0f; accB[i] = 0.0f; }

    // prologue load (compiler-visible; it grades vmcnt itself)
    float4 MA = p[0];
    float4 MB = p[64];

    __syncthreads();                             // x tile ready

    // fuzzy-AND for batch bi: 16 pk instrs (2 c x 4 v), mul-only
#define PAIR(XC, bi, MAr, MBr) do { \
    float t0, t1, t2, t3; \
    PKMUL(t0, MAr.x, XC.z);   /* m1(v0,v1) * (1-x)(v0,v1)  [cA] */ \
    PKMUL(t1, MAr.z, XC.x);   /* m2(v0,v1) * x(v0,v1)      [cA] */ \
    PKMUL(t2, MAr.y, XC.w);   /* m1(v2,v3) * (1-x)(v2,v3)  [cA] */ \
    PKMUL(t3, MAr.w, XC.y);   /* m2(v2,v3) * x(v2,v3)      [cA] */ \
    PKMAX(accA[bi], t0); PKMAX(accA[bi], t1); \
    PKMAX(accA[bi], t2); PKMAX(accA[bi], t3); \
    PKMUL(t0, MBr.x, XC.z);   /* same for cB */ \
    PKMUL(t1, MBr.z, XC.x); \
    PKMUL(t2, MBr.y, XC.w); \
    PKMUL(t3, MBr.w, XC.y); \
    PKMAX(accB[bi], t0); PKMAX(accB[bi], t1); \
    PKMAX(accB[bi], t2); PKMAX(accB[bi], t3); \
    } while (0)

#pragma unroll
    for (int q = 0; q < 8; ++q) {
        // batch the 8 x ds_reads (independent, in flight together)
        float4 xc0 = xs4[0 * 64 + vq0 + q];
        float4 xc1 = xs4[1 * 64 + vq0 + q];
        float4 xc2 = xs4[2 * 64 + vq0 + q];
        float4 xc3 = xs4[3 * 64 + vq0 + q];
        float4 xc4 = xs4[4 * 64 + vq0 + q];
        float4 xc5 = xs4[5 * 64 + vq0 + q];
        float4 xc6 = xs4[6 * 64 + vq0 + q];
        float4 xc7 = xs4[7 * 64 + vq0 + q];
        // depth-1 prefetch of next row (compiler-visible)
        float4 NA, NB;
        if (q < 7) {
            NA = p[(size_t)(q + 1) * C_];
            NB = p[(size_t)(q + 1) * C_ + 64];
        }
        // pin current AFTER next's issue (R8-validated component pin)
        asm volatile("" : "+v"(MA.x), "+v"(MA.y), "+v"(MA.z), "+v"(MA.w),
                          "+v"(MB.x), "+v"(MB.y), "+v"(MB.z), "+v"(MB.w));
        PAIR(xc0, 0, MA, MB);
        PAIR(xc1, 1, MA, MB);
        PAIR(xc2, 2, MA, MB);
        PAIR(xc3, 3, MA, MB);
        PAIR(xc4, 4, MA, MB);
        PAIR(xc5, 5, MA, MB);
        PAIR(xc6, 6, MA, MB);
        PAIR(xc7, 7, MA, MB);
        if (q < 7) { MA = NA; MB = NB; }
    }
#undef PAIR

    // fold packed accumulators to f32 scalars (scalar cvt, outside hot loop)
    float mA[BPB], mB[BPB];
#pragma unroll
    for (int bi = 0; bi < BPB; ++bi) {
        h16x2 ha = __builtin_bit_cast(h16x2, accA[bi]);
        h16x2 hb = __builtin_bit_cast(h16x2, accB[bi]);
        mA[bi] = fmaxf((float)ha.x, (float)ha.y);
        mB[bi] = fmaxf((float)hb.x, (float)hb.y);
    }

    // ---- epilogue: combine 8 v-eighths, weight, sum over c, accumulate ----
#pragma unroll
    for (int bi = 0; bi < BPB; ++bi) {
        red[(wave * 64 + lane) * 17 + bi * 2 + 0] = mA[bi];
        red[(wave * 64 + lane) * 17 + bi * 2 + 1] = mB[bi];
    }
    __syncthreads();

    if (wave < 2) {                              // wave w finishes cc = w
        const float rwc = rw[chunk * 128 + wave * 64 + lane];
        float con0, con1, con2, con3, con4, con5, con6, con7;
#define FIN(bi, CON) do { \
        float mm = red[(0 * 64 + lane) * 17 + (bi) * 2 + wave]; \
        _Pragma("unroll") \
        for (int wv = 1; wv < 8; ++wv) \
            mm = fmaxf(mm, red[(wv * 64 + lane) * 17 + (bi) * 2 + wave]); \
        float v = rwc * (1.0f - mm); \
        v += __shfl_xor(v, 1, 64);  v += __shfl_xor(v, 2, 64); \
        v += __shfl_xor(v, 4, 64);  v += __shfl_xor(v, 8, 64); \
        v += __shfl_xor(v, 16, 64); v += __shfl_xor(v, 32, 64); \
        CON = v; } while (0)
        FIN(0, con0); FIN(1, con1); FIN(2, con2); FIN(3, con3);
        FIN(4, con4); FIN(5, con5); FIN(6, con6); FIN(7, con7);
#undef FIN
        float t0 = (lane & 1) ? con1 : con0;
        float t1 = (lane & 1) ? con3 : con2;
        float t2 = (lane & 1) ? con5 : con4;
        float t3 = (lane & 1) ? con7 : con6;
        float u0 = (lane & 2) ? t1 : t0;
        float u1 = (lane & 2) ? t3 : t2;
        float sel = (lane & 4) ? u1 : u0;
        if (lane < 8)
            atomicAdd(&out[bg * BPB + lane], sel);   // 8 adds/element total
    }
}

// ---------- fallback (ws too small): naive but correct ----------
__global__ __launch_bounds__(256) void k_naive(const float* __restrict__ x0,
                                               const float* __restrict__ conj,
                                               const float* __restrict__ rw,
                                               float* __restrict__ out) {
    int b = blockIdx.x;
    int t = threadIdx.x;
    __shared__ float red[256];
    float acc = 0.0f;
    for (int c = t; c < C_; c += 256) {
        float mm = 0.0f;
        for (int v = 0; v < V_; ++v) {
            float mu1 = 1.0f / (1.0f + expf(-conj[(size_t)c * TWOV + v]));
            float mu2 = 1.0f / (1.0f + expf(-conj[(size_t)c * TWOV + V_ + v]));
            float x = x0[(size_t)b * V_ + v];
            mm = fmaxf(mm, fmaxf(mu1 * (1.0f - x), mu2 * x));
        }
        acc += rw[c] * (1.0f - mm);
    }
    red[t] = acc;
    __syncthreads();
    for (int s = 128; s > 0; s >>= 1) {
        if (t < s) red[t] += red[t + s];
        __syncthreads();
    }
    if (t == 0) out[b] = 5.0f + red[0];
}

extern "C" void kernel_launch(void* const* d_in, const int* in_sizes, int n_in,
                              void* d_out, int out_size, void* d_ws, size_t ws_size,
                              hipStream_t stream) {
    const float* x0   = (const float*)d_in[0];
    const float* conj = (const float*)d_in[1];
    const float* rw   = (const float*)d_in[2];
    float* out = (float*)d_out;

    const size_t need = (size_t)64 * C_ * 16;   // muH: 512 KB

    if (ws_size < need) {
        k_naive<<<B_, 256, 0, stream>>>(x0, conj, rw, out);
        return;
    }

    float4* muH = (float4*)d_ws;

    k_prep<<<64, 512, 0, stream>>>(conj, muH, out);
    dim3 grid(NBG, NCH);      // 128 x 4 = 512 blocks = 2/CU, 16 waves/CU
    k_main<<<grid, 512, 0, stream>>>(x0, muH, rw, out);
}